// Round 1
// baseline (81.882 us; speedup 1.0000x reference)
//
#include <hip/hip_runtime.h>
#include <math.h>

#define KNN 8
#define CF 16
#define SRS 128
#define NRAYS 4096

__global__ __launch_bounds__(128) void pvr_fused_kernel(
    const float* __restrict__ points_feat,   // [N_PTS, 16]
    const int*   __restrict__ indices,       // [N, 8]
    const float* __restrict__ dists,         // [N, 8]
    const float* __restrict__ w_rgb,         // [16, 3]
    const float* __restrict__ w_sigma,       // [16, 1]
    const float* __restrict__ delta,         // [R, SR]
    const float* __restrict__ z_vals,        // [R, SR]
    float* __restrict__ out)                 // [R, 5]
{
    const int ray  = blockIdx.x;
    const int t    = threadIdx.x;      // sample index within ray (0..127)
    const int lane = t & 63;
    const int wid  = t >> 6;
    const long long n = (long long)ray * SRS + t;  // global sample id

    __shared__ float s_wrgb[CF * 3];
    __shared__ float s_wsig[CF];
    __shared__ float s_wavetot;        // inclusive product of wave 0
    __shared__ float s_red[2][5];      // per-wave partial sums

    if (t < CF * 3)                 s_wrgb[t] = w_rgb[t];
    else if (t < CF * 3 + CF)       s_wsig[t - CF * 3] = w_sigma[t - CF * 3];
    __syncthreads();

    // ---- load per-sample dists / indices (32B contiguous per thread) ----
    const float4* dv = (const float4*)(dists + n * KNN);
    float4 d0 = dv[0], d1 = dv[1];
    const int4* iv = (const int4*)(indices + n * KNN);
    int4 i0 = iv[0], i1 = iv[1];

    float wk[KNN];
    wk[0] = 1.0f / (d0.x + 1e-7f);
    wk[1] = 1.0f / (d0.y + 1e-7f);
    wk[2] = 1.0f / (d0.z + 1e-7f);
    wk[3] = 1.0f / (d0.w + 1e-7f);
    wk[4] = 1.0f / (d1.x + 1e-7f);
    wk[5] = 1.0f / (d1.y + 1e-7f);
    wk[6] = 1.0f / (d1.z + 1e-7f);
    wk[7] = 1.0f / (d1.w + 1e-7f);
    float wsum = wk[0] + wk[1] + wk[2] + wk[3] + wk[4] + wk[5] + wk[6] + wk[7];
    float winv = 1.0f / wsum;

    int idx[KNN] = {i0.x, i0.y, i0.z, i0.w, i1.x, i1.y, i1.z, i1.w};

    // ---- KNN gather + weighted aggregation into feat[16] (registers) ----
    float feat[CF];
#pragma unroll
    for (int c = 0; c < CF; ++c) feat[c] = 0.0f;

#pragma unroll
    for (int k = 0; k < KNN; ++k) {
        const float4* p = (const float4*)(points_feat + (long long)idx[k] * CF);
        float4 f0 = p[0], f1 = p[1], f2 = p[2], f3 = p[3];
        float w = wk[k] * winv;
        feat[0]  = fmaf(w, f0.x, feat[0]);
        feat[1]  = fmaf(w, f0.y, feat[1]);
        feat[2]  = fmaf(w, f0.z, feat[2]);
        feat[3]  = fmaf(w, f0.w, feat[3]);
        feat[4]  = fmaf(w, f1.x, feat[4]);
        feat[5]  = fmaf(w, f1.y, feat[5]);
        feat[6]  = fmaf(w, f1.z, feat[6]);
        feat[7]  = fmaf(w, f1.w, feat[7]);
        feat[8]  = fmaf(w, f2.x, feat[8]);
        feat[9]  = fmaf(w, f2.y, feat[9]);
        feat[10] = fmaf(w, f2.z, feat[10]);
        feat[11] = fmaf(w, f2.w, feat[11]);
        feat[12] = fmaf(w, f3.x, feat[12]);
        feat[13] = fmaf(w, f3.y, feat[13]);
        feat[14] = fmaf(w, f3.z, feat[14]);
        feat[15] = fmaf(w, f3.w, feat[15]);
    }

    // ---- small head: rgb = sigmoid(feat @ w_rgb), sigma = relu(feat @ w_sigma) ----
    float rgb[3];
#pragma unroll
    for (int j = 0; j < 3; ++j) {
        float s = 0.0f;
#pragma unroll
        for (int c = 0; c < CF; ++c) s = fmaf(feat[c], s_wrgb[c * 3 + j], s);
        rgb[j] = 1.0f / (1.0f + expf(-s));
    }
    float ssig = 0.0f;
#pragma unroll
    for (int c = 0; c < CF; ++c) ssig = fmaf(feat[c], s_wsig[c], ssig);
    float sigma = fmaxf(ssig, 0.0f);

    float del = delta[n];
    float zv  = z_vals[n];
    float alpha = 1.0f - expf(-sigma * del);

    // ---- exclusive prefix product of (1 - alpha + 1e-10) across 128 samples ----
    float a = 1.0f - alpha + 1e-10f;
    float p = a;
#pragma unroll
    for (int off = 1; off < 64; off <<= 1) {
        float v = __shfl_up(p, off, 64);
        if (lane >= off) p *= v;
    }
    if (wid == 0 && lane == 63) s_wavetot = p;   // total product of wave 0
    __syncthreads();

    float pm1  = __shfl_up(p, 1, 64);
    float excl = (lane == 0) ? 1.0f : pm1;
    if (wid == 1) excl *= s_wavetot;

    float wts = alpha * excl;

    // ---- per-ray reductions: sum wts*rgb (3), wts*z, wts ----
    float v0 = wts * rgb[0];
    float v1 = wts * rgb[1];
    float v2 = wts * rgb[2];
    float v3 = wts * zv;
    float v4 = wts;
#pragma unroll
    for (int off = 32; off >= 1; off >>= 1) {
        v0 += __shfl_down(v0, off, 64);
        v1 += __shfl_down(v1, off, 64);
        v2 += __shfl_down(v2, off, 64);
        v3 += __shfl_down(v3, off, 64);
        v4 += __shfl_down(v4, off, 64);
    }
    if (lane == 0) {
        s_red[wid][0] = v0;
        s_red[wid][1] = v1;
        s_red[wid][2] = v2;
        s_red[wid][3] = v3;
        s_red[wid][4] = v4;
    }
    __syncthreads();

    if (t == 0) {
        float r0  = s_red[0][0] + s_red[1][0];
        float r1  = s_red[0][1] + s_red[1][1];
        float r2  = s_red[0][2] + s_red[1][2];
        float dep = s_red[0][3] + s_red[1][3];
        float acc = s_red[0][4] + s_red[1][4];
        float bg  = 1.0f - acc;
        float* o = out + (long long)ray * 5;
        o[0] = r0 + bg;
        o[1] = r1 + bg;
        o[2] = r2 + bg;
        o[3] = dep;
        o[4] = acc;
    }
}

extern "C" void kernel_launch(void* const* d_in, const int* in_sizes, int n_in,
                              void* d_out, int out_size, void* d_ws, size_t ws_size,
                              hipStream_t stream) {
    const float* points_feat = (const float*)d_in[0];
    const int*   indices     = (const int*)d_in[1];
    const float* dists       = (const float*)d_in[2];
    const float* w_rgb       = (const float*)d_in[3];
    const float* w_sigma     = (const float*)d_in[4];
    const float* delta       = (const float*)d_in[5];
    const float* z_vals      = (const float*)d_in[6];
    float* out = (float*)d_out;

    pvr_fused_kernel<<<NRAYS, 128, 0, stream>>>(
        points_feat, indices, dists, w_rgb, w_sigma, delta, z_vals, out);
}

// Round 3
// 75.661 us; speedup vs baseline: 1.0822x; 1.0822x over previous
//
#include <hip/hip_runtime.h>
#include <math.h>

#define KNN 8
#define CF 16
#define SRS 128
#define NRAYS 4096
#define TPB 512   // 4 threads per sample, 128 samples per ray

__global__ __launch_bounds__(TPB) void pvr_fused_kernel(
    const float* __restrict__ points_feat,   // [N_PTS, 16]
    const int*   __restrict__ indices,       // [N, 8]
    const float* __restrict__ dists,         // [N, 8]
    const float* __restrict__ w_rgb,         // [16, 3]
    const float* __restrict__ w_sigma,       // [16, 1]
    const float* __restrict__ delta,         // [R, SR]
    const float* __restrict__ z_vals,        // [R, SR]
    float* __restrict__ out)                 // [R, 5]
{
    const int ray = blockIdx.x;
    const int t   = threadIdx.x;
    const int s   = t >> 2;                    // sample within ray (0..127)
    const int j   = t & 3;                     // neighbor-pair id (0..3)
    const long long n = (long long)ray * SRS + s;

    __shared__ float s_wrgb[CF * 3];
    __shared__ float s_wsig[CF];
    __shared__ float s_sig[SRS];
    __shared__ float s_rgbv[3][SRS];
    __shared__ float s_wavetot;
    __shared__ float s_red[2][5];

    if (t < CF * 3)            s_wrgb[t] = w_rgb[t];
    else if (t < CF * 3 + CF)  s_wsig[t - CF * 3] = w_sigma[t - CF * 3];

    // ---- per-thread: 2 neighbors. Coalesced int2/float2 stream loads. ----
    const int2   i2 = ((const int2*)indices)[n * 4 + j];
    const float2 d2 = ((const float2*)dists)[n * 4 + j];

    // issue both 64-B row gathers fully before consuming (2 lines in flight)
    const float4* pA = (const float4*)(points_feat + (long long)i2.x * CF);
    const float4* pB = (const float4*)(points_feat + (long long)i2.y * CF);
    float4 a0 = pA[0], a1 = pA[1], a2 = pA[2], a3 = pA[3];
    float4 b0 = pB[0], b1 = pB[1], b2 = pB[2], b3 = pB[3];

    float w0 = 1.0f / (d2.x + 1e-7f);
    float w1 = 1.0f / (d2.y + 1e-7f);
    float wsum = w0 + w1;
    wsum += __shfl_xor(wsum, 1);
    wsum += __shfl_xor(wsum, 2);
    const float winv = 1.0f / wsum;

    float feat[CF];
    feat[0]  = fmaf(w0, a0.x, w1 * b0.x);
    feat[1]  = fmaf(w0, a0.y, w1 * b0.y);
    feat[2]  = fmaf(w0, a0.z, w1 * b0.z);
    feat[3]  = fmaf(w0, a0.w, w1 * b0.w);
    feat[4]  = fmaf(w0, a1.x, w1 * b1.x);
    feat[5]  = fmaf(w0, a1.y, w1 * b1.y);
    feat[6]  = fmaf(w0, a1.z, w1 * b1.z);
    feat[7]  = fmaf(w0, a1.w, w1 * b1.w);
    feat[8]  = fmaf(w0, a2.x, w1 * b2.x);
    feat[9]  = fmaf(w0, a2.y, w1 * b2.y);
    feat[10] = fmaf(w0, a2.z, w1 * b2.z);
    feat[11] = fmaf(w0, a2.w, w1 * b2.w);
    feat[12] = fmaf(w0, a3.x, w1 * b3.x);
    feat[13] = fmaf(w0, a3.y, w1 * b3.y);
    feat[14] = fmaf(w0, a3.z, w1 * b3.z);
    feat[15] = fmaf(w0, a3.w, w1 * b3.w);

    // butterfly-reduce the 16 partial features across the 4-lane group
#pragma unroll
    for (int c = 0; c < CF; ++c) {
        feat[c] += __shfl_xor(feat[c], 1);
        feat[c] += __shfl_xor(feat[c], 2);
    }

    __syncthreads();   // weights staged; also orders LDS writes below

    // ---- head (computed redundantly by the 4 lanes of each sample) ----
    float rgb[3];
#pragma unroll
    for (int q = 0; q < 3; ++q) {
        float acc = 0.0f;
#pragma unroll
        for (int c = 0; c < CF; ++c) acc = fmaf(feat[c], s_wrgb[c * 3 + q], acc);
        rgb[q] = 1.0f / (1.0f + expf(-acc * winv));
    }
    float ssig = 0.0f;
#pragma unroll
    for (int c = 0; c < CF; ++c) ssig = fmaf(feat[c], s_wsig[c], ssig);
    ssig *= winv;

    if (j == 0) {
        s_sig[s]     = ssig;
        s_rgbv[0][s] = rgb[0];
        s_rgbv[1][s] = rgb[1];
        s_rgbv[2][s] = rgb[2];
    }
    __syncthreads();

    // ---- phase 2: per-ray scan + reductions on first 128 threads ----
    float p = 0.0f, alpha = 0.0f, zv = 0.0f;
    float r0 = 0.0f, r1 = 0.0f, r2 = 0.0f;
    const int lane = t & 63;
    const int wid  = t >> 6;
    if (t < SRS) {
        const long long m = (long long)ray * SRS + t;
        const float del = __builtin_nontemporal_load(delta  + m);
        zv              = __builtin_nontemporal_load(z_vals + m);
        const float sg  = fmaxf(s_sig[t], 0.0f);
        alpha = 1.0f - expf(-sg * del);
        r0 = s_rgbv[0][t]; r1 = s_rgbv[1][t]; r2 = s_rgbv[2][t];

        // inclusive prefix product of (1 - alpha + 1e-10) within wave
        p = 1.0f - alpha + 1e-10f;
#pragma unroll
        for (int off = 1; off < 64; off <<= 1) {
            float v = __shfl_up(p, off, 64);
            if (lane >= off) p *= v;
        }
        if (wid == 0 && lane == 63) s_wavetot = p;
    }
    __syncthreads();

    if (t < SRS) {
        float pm1  = __shfl_up(p, 1, 64);
        float excl = (lane == 0) ? 1.0f : pm1;
        if (wid == 1) excl *= s_wavetot;
        const float wts = alpha * excl;

        float v0 = wts * r0;
        float v1 = wts * r1;
        float v2 = wts * r2;
        float v3 = wts * zv;
        float v4 = wts;
#pragma unroll
        for (int off = 32; off >= 1; off >>= 1) {
            v0 += __shfl_down(v0, off, 64);
            v1 += __shfl_down(v1, off, 64);
            v2 += __shfl_down(v2, off, 64);
            v3 += __shfl_down(v3, off, 64);
            v4 += __shfl_down(v4, off, 64);
        }
        if (lane == 0) {
            s_red[wid][0] = v0;
            s_red[wid][1] = v1;
            s_red[wid][2] = v2;
            s_red[wid][3] = v3;
            s_red[wid][4] = v4;
        }
    }
    __syncthreads();

    if (t == 0) {
        float q0  = s_red[0][0] + s_red[1][0];
        float q1  = s_red[0][1] + s_red[1][1];
        float q2  = s_red[0][2] + s_red[1][2];
        float dep = s_red[0][3] + s_red[1][3];
        float acc = s_red[0][4] + s_red[1][4];
        float bg  = 1.0f - acc;
        float* o = out + (long long)ray * 5;
        o[0] = q0 + bg;
        o[1] = q1 + bg;
        o[2] = q2 + bg;
        o[3] = dep;
        o[4] = acc;
    }
}

extern "C" void kernel_launch(void* const* d_in, const int* in_sizes, int n_in,
                              void* d_out, int out_size, void* d_ws, size_t ws_size,
                              hipStream_t stream) {
    const float* points_feat = (const float*)d_in[0];
    const int*   indices     = (const int*)d_in[1];
    const float* dists       = (const float*)d_in[2];
    const float* w_rgb       = (const float*)d_in[3];
    const float* w_sigma     = (const float*)d_in[4];
    const float* delta       = (const float*)d_in[5];
    const float* z_vals      = (const float*)d_in[6];
    float* out = (float*)d_out;

    pvr_fused_kernel<<<NRAYS, TPB, 0, stream>>>(
        points_feat, indices, dists, w_rgb, w_sigma, delta, z_vals, out);
}